// Round 7
// baseline (543.887 us; speedup 1.0000x reference)
//
#include <hip/hip_runtime.h>
#include <math.h>

typedef unsigned short u16;
typedef short s16x8 __attribute__((ext_vector_type(8)));  // 8 bf16 lanes (4 VGPRs)
typedef float f32x4 __attribute__((ext_vector_type(4)));

// B=2, S=2048, D=2048, H=16, HD=128; qkv row width = 6144
#define ATTN_SCALE 0.08838834764831845f
#define NEG_BIG -1.0e30f

__device__ __forceinline__ u16 f2bf(float f) {
  union { float f; unsigned u; } c; c.f = f;
  return (u16)((c.u + 0x7fffu + ((c.u >> 16) & 1u)) >> 16);  // RNE
}
__device__ __forceinline__ float bf2f(u16 v) {
  union { unsigned u; float f; } c; c.u = ((unsigned)v) << 16;
  return c.f;
}
__device__ __forceinline__ f32x4 mfma16(s16x8 a, s16x8 b, f32x4 c) {
  return __builtin_amdgcn_mfma_f32_16x16x32_bf16(a, b, c, 0, 0, 0);
}

// -------- fp32 [R][C] -> bf16 out[C][R] transpose+cast ------------------
__global__ __launch_bounds__(256) void k_transpose_cast(const float* __restrict__ in,
                                                        u16* __restrict__ out,
                                                        int R, int C) {
  __shared__ __attribute__((aligned(16))) u16 tile[32][33];
  const int c0 = blockIdx.x * 32, r0 = blockIdx.y * 32;
  const int tx = threadIdx.x, ty = threadIdx.y;
#pragma unroll
  for (int i = 0; i < 4; ++i)
    tile[ty + 8 * i][tx] = f2bf(in[(r0 + ty + 8 * i) * C + c0 + tx]);
  __syncthreads();
#pragma unroll
  for (int i = 0; i < 4; ++i)
    out[(c0 + ty + 8 * i) * R + r0 + tx] = tile[tx][ty + 8 * i];
}

// ---------------- V -> V^T per (b,h): vt[bh][d][s] = qkv_v[b,s,h,d] ------
__global__ __launch_bounds__(256) void k_vtrans(const u16* __restrict__ qkv,
                                                u16* __restrict__ vt) {
  __shared__ __attribute__((aligned(16))) u16 tile[32][33];
  const int bh = blockIdx.z, b = bh >> 4, h = bh & 15;
  const int s0 = blockIdx.x * 32, d0 = blockIdx.y * 32;
  const int tx = threadIdx.x, ty = threadIdx.y;
#pragma unroll
  for (int i = 0; i < 4; ++i) {
    const int s = s0 + ty + 8 * i;
    tile[ty + 8 * i][tx] = qkv[(b * 2048 + s) * 6144 + 4096 + h * 128 + d0 + tx];
  }
  __syncthreads();
#pragma unroll
  for (int i = 0; i < 4; ++i) {
    const int d = d0 + ty + 8 * i;
    vt[bh * 262144 + d * 2048 + s0 + tx] = tile[tx][ty + 8 * i];
  }
}

// ---------------- RoPE in-place on Q and K sections of qkv (bf16) -------
__global__ __launch_bounds__(256) void k_rope(u16* __restrict__ qkv) {
  const int id = blockIdx.x * 256 + threadIdx.x;  // 8,388,608 threads
  const int j = id & 63;
  const int h = (id >> 6) & 15;
  const int sec = (id >> 10) & 1;
  const int m = id >> 11;  // b*2048+s
  const int s = m & 2047;
  const int base = m * 6144 + sec * 2048 + h * 128 + j;
  const float q0 = bf2f(qkv[base]);
  const float q1 = bf2f(qkv[base + 64]);
  const float inv = (float)exp((double)j * -0.14391156831212788);  // 10000^(-j/64)
  const float ang = (float)s * inv;
  float c, sn;
  sincosf(ang, &sn, &c);  // FIXED: sincosf(x, SIN*, COS*) — sin is FIRST
  qkv[base]      = f2bf(q0 * c - q1 * sn);
  qkv[base + 64] = f2bf(q1 * c + q0 * sn);
}

// ------- GEMM: C[M][N] = A[M][K] * BT[N][K]^T  (fp32 acc) ---------------
// A_T = float (cast to bf16 during staging) or u16; OUT_T = u16 or float
template <typename A_T, typename OUT_T>
__global__ __launch_bounds__(256) void k_gemm_bt(const A_T* __restrict__ A, int lda,
                                                 const u16* __restrict__ BT,
                                                 OUT_T* __restrict__ C, int ldc,
                                                 int K) {
  __shared__ __attribute__((aligned(16))) u16 As[128 * 40];
  __shared__ __attribute__((aligned(16))) u16 Bs[128 * 40];
  const int tid = threadIdx.x;
  const int lane = tid & 63, wave = tid >> 6;
  const int lm = lane & 15, quad = lane >> 4;
  const int wm = wave >> 1, wn = wave & 1;
  const int m0 = blockIdx.y * 128, n0 = blockIdx.x * 128;

  const f32x4 fzero = {0.f, 0.f, 0.f, 0.f};
  f32x4 acc[4][4];
#pragma unroll
  for (int i = 0; i < 4; ++i)
#pragma unroll
    for (int j = 0; j < 4; ++j) acc[i][j] = fzero;

  for (int k0 = 0; k0 < K; k0 += 32) {
    __syncthreads();
#pragma unroll
    for (int i = 0; i < 2; ++i) {
      const int seg = tid + 256 * i;
      const int row = seg >> 2, c8 = (seg & 3) * 8;
      if constexpr (sizeof(A_T) == 4) {  // fp32 A: load 8 floats, pack to bf16
        const float* Af = (const float*)A;
        const float4 u = *(const float4*)&Af[(m0 + row) * lda + k0 + c8];
        const float4 w = *(const float4*)&Af[(m0 + row) * lda + k0 + c8 + 4];
        uint4 pk;
        pk.x = (unsigned)f2bf(u.x) | ((unsigned)f2bf(u.y) << 16);
        pk.y = (unsigned)f2bf(u.z) | ((unsigned)f2bf(u.w) << 16);
        pk.z = (unsigned)f2bf(w.x) | ((unsigned)f2bf(w.y) << 16);
        pk.w = (unsigned)f2bf(w.z) | ((unsigned)f2bf(w.w) << 16);
        *(uint4*)&As[row * 40 + c8] = pk;
      } else {
        *(uint4*)&As[row * 40 + c8] =
            *(const uint4*)&((const u16*)A)[(m0 + row) * lda + k0 + c8];
      }
      *(uint4*)&Bs[row * 40 + c8] = *(const uint4*)&BT[(n0 + row) * K + k0 + c8];
    }
    __syncthreads();
    s16x8 af[4], bfr[4];
#pragma unroll
    for (int t = 0; t < 4; ++t) {
      af[t]  = *(const s16x8*)&As[(wm * 64 + t * 16 + lm) * 40 + quad * 8];
      bfr[t] = *(const s16x8*)&Bs[(wn * 64 + t * 16 + lm) * 40 + quad * 8];
    }
#pragma unroll
    for (int mt = 0; mt < 4; ++mt)
#pragma unroll
      for (int nt = 0; nt < 4; ++nt)
        acc[mt][nt] = mfma16(af[mt], bfr[nt], acc[mt][nt]);
  }
  // C/D layout: row = quad*4 + r, col = lm (m89/m91)
#pragma unroll
  for (int mt = 0; mt < 4; ++mt)
#pragma unroll
    for (int nt = 0; nt < 4; ++nt)
#pragma unroll
      for (int r = 0; r < 4; ++r) {
        const float v = acc[mt][nt][r];
        const int idx = (m0 + wm * 64 + mt * 16 + quad * 4 + r) * ldc +
                        n0 + wn * 64 + nt * 16 + lm;
        if constexpr (sizeof(OUT_T) == 2) C[idx] = f2bf(v);
        else                              C[idx] = v;
      }
}

// ---------------- causal flash attention (bf16 in/out) ------------------
// S^T = K*Q^T: C-layout col = q = lm -> softmax state lane-uniform.
// P -> wave-private LDS bounce (barrier-protected) -> B-operand of
// O^T = V^T * P^T.  Output written IN PLACE into the Q-section of qkv.
__global__ __launch_bounds__(256) void k_attn(u16* __restrict__ qkv,
                                              const u16* __restrict__ vt) {
  __shared__ __attribute__((aligned(16))) u16 Ks[32 * 136];     // [32 keys][128 d]
  __shared__ __attribute__((aligned(16))) u16 Vs[128 * 40];     // [128 d][32 keys]
  __shared__ __attribute__((aligned(16))) u16 Ps[4 * 16 * 40];  // per-wave P[q][key]
  const int qtile = blockIdx.x, bh = blockIdx.y;
  const int b = bh >> 4, h = bh & 15;
  const int tid = threadIdx.x;
  const int lane = tid & 63, wave = tid >> 6;
  const int lm = lane & 15, quad = lane >> 4;
  const int qb = qtile * 64;
  const int qrow = qb + wave * 16 + lm;
  const int pbase = wave * 640;

  s16x8 qfrag[4];
  const int qoff = (b * 2048 + qrow) * 6144 + h * 128;
#pragma unroll
  for (int c = 0; c < 4; ++c)
    qfrag[c] = *(const s16x8*)&qkv[qoff + c * 32 + quad * 8];

  const f32x4 fzero = {0.f, 0.f, 0.f, 0.f};
  f32x4 o[8];
#pragma unroll
  for (int dt = 0; dt < 8; ++dt) o[dt] = fzero;
  float m_run = NEG_BIG, l_run = 0.f;

  const int nkt = (qb >> 5) + 2;  // key tiles covering 0 .. qb+63
  for (int kt = 0; kt < nkt; ++kt) {
    const int kt0 = kt * 32;
    __syncthreads();
#pragma unroll
    for (int i = 0; i < 2; ++i) {
      const int seg = tid + 256 * i;
      {  // K tile
        const int row = seg >> 4, c8 = (seg & 15) * 8;
        *(uint4*)&Ks[row * 136 + c8] =
            *(const uint4*)&qkv[(b * 2048 + kt0 + row) * 6144 + 2048 + h * 128 + c8];
      }
      {  // V^T tile
        const int row = seg >> 2, c8 = (seg & 3) * 8;
        *(uint4*)&Vs[row * 40 + c8] =
            *(const uint4*)&vt[bh * 262144 + row * 2048 + kt0 + c8];
      }
    }
    __syncthreads();

    f32x4 sa[2];
    sa[0] = fzero; sa[1] = fzero;
#pragma unroll
    for (int ss = 0; ss < 2; ++ss)
#pragma unroll
      for (int c = 0; c < 4; ++c) {
        s16x8 a = *(const s16x8*)&Ks[(ss * 16 + lm) * 136 + c * 32 + quad * 8];
        sa[ss] = mfma16(a, qfrag[c], sa[ss]);
      }

    float p[2][4];
    float vmax = NEG_BIG;
#pragma unroll
    for (int ss = 0; ss < 2; ++ss)
#pragma unroll
      for (int r = 0; r < 4; ++r) {
        const int kg = kt0 + ss * 16 + quad * 4 + r;
        float v = sa[ss][r] * ATTN_SCALE;
        if (kg > qrow) v = NEG_BIG;
        p[ss][r] = v;
        vmax = fmaxf(vmax, v);
      }
    vmax = fmaxf(vmax, __shfl_xor(vmax, 16, 64));
    vmax = fmaxf(vmax, __shfl_xor(vmax, 32, 64));
    const float m_new = fmaxf(m_run, vmax);
    const float alpha = __expf(m_run - m_new);
    float rsum = 0.f;
#pragma unroll
    for (int ss = 0; ss < 2; ++ss)
#pragma unroll
      for (int r = 0; r < 4; ++r) {
        p[ss][r] = __expf(p[ss][r] - m_new);  // masked: exp(-huge) = 0
        rsum += p[ss][r];
      }
    rsum += __shfl_xor(rsum, 16, 64);
    rsum += __shfl_xor(rsum, 32, 64);
    l_run = l_run * alpha + rsum;
    m_run = m_new;
#pragma unroll
    for (int dt = 0; dt < 8; ++dt) o[dt] *= alpha;

    // P -> LDS: Ps[q=lm][key = ss*16 + quad*4 + r]
#pragma unroll
    for (int ss = 0; ss < 2; ++ss)
#pragma unroll
      for (int r = 0; r < 4; ++r)
        Ps[pbase + lm * 40 + ss * 16 + quad * 4 + r] = f2bf(p[ss][r]);

    __syncthreads();  // cross-lane LDS RAW guard

    const s16x8 pv = *(const s16x8*)&Ps[pbase + lm * 40 + quad * 8];

#pragma unroll
    for (int dt = 0; dt < 8; ++dt) {
      s16x8 a = *(const s16x8*)&Vs[(dt * 16 + lm) * 40 + quad * 8];
      o[dt] = mfma16(a, pv, o[dt]);
    }
  }

  const float inv_l = 1.0f / l_run;
#pragma unroll
  for (int dt = 0; dt < 8; ++dt)
#pragma unroll
    for (int r = 0; r < 4; ++r)
      qkv[qoff + dt * 16 + quad * 4 + r] = f2bf(o[dt][r] * inv_l);
}

// ---------------- host launcher ----------------------------------------
extern "C" void kernel_launch(void* const* d_in, const int* in_sizes, int n_in,
                              void* d_out, int out_size, void* d_ws, size_t ws_size,
                              hipStream_t stream) {
  const float* hidden = (const float*)d_in[0];  // [4096][2048] fp32
  const float* w_qkv  = (const float*)d_in[1];  // [2048][6144] fp32
  const float* w_o    = (const float*)d_in[2];  // [2048][2048] fp32
  float* out = (float*)d_out;                   // [4096][2048] fp32
  u16* ws = (u16*)d_ws;

  // Overlay (peak 72 MB):
  //   qkv   : ws[0 .. 25165824)            48 MB, whole session
  //   wqkvT : ws[25165824 .. 37748736)     24 MB, GEMM1 only
  //   vt    : ws[25165824 .. 33554432)     16 MB, overlays wqkvT (dead)
  //   woT   : ws[33554432 .. 37748736)      8 MB, overlays wqkvT tail (dead)
  u16* qkv   = ws;
  u16* wqkvT = ws + 25165824;
  u16* vt    = ws + 25165824;
  u16* woT   = ws + 33554432;

  dim3 tb(32, 8);
  k_transpose_cast<<<dim3(192, 64), tb, 0, stream>>>(w_qkv, wqkvT, 2048, 6144);
  k_gemm_bt<float, u16><<<dim3(48, 32), 256, 0, stream>>>(hidden, 2048, wqkvT,
                                                          qkv, 6144, 2048);
  k_rope<<<32768, 256, 0, stream>>>(qkv);
  k_vtrans<<<dim3(64, 4, 32), tb, 0, stream>>>(qkv, vt);
  k_transpose_cast<<<dim3(64, 64), tb, 0, stream>>>(w_o, woT, 2048, 2048);
  k_attn<<<dim3(32, 32), 256, 0, stream>>>(qkv, vt);
  k_gemm_bt<u16, float><<<dim3(16, 32), 256, 0, stream>>>(qkv, 6144, woT,
                                                          out, 2048, 2048);
}

// Round 8
// 496.796 us; speedup vs baseline: 1.0948x; 1.0948x over previous
//
#include <hip/hip_runtime.h>
#include <math.h>

typedef unsigned short u16;
typedef short s16x8 __attribute__((ext_vector_type(8)));  // 8 bf16 lanes (4 VGPRs)
typedef float f32x4 __attribute__((ext_vector_type(4)));

// B=2, S=2048, D=2048, H=16, HD=128; qkv row width = 6144
#define ATTN_SCALE 0.08838834764831845f
#define NEG_BIG -1.0e30f

__device__ __forceinline__ u16 f2bf(float f) {
  union { float f; unsigned u; } c; c.f = f;
  return (u16)((c.u + 0x7fffu + ((c.u >> 16) & 1u)) >> 16);  // RNE
}
__device__ __forceinline__ float bf2f(u16 v) {
  union { unsigned u; float f; } c; c.u = ((unsigned)v) << 16;
  return c.f;
}
__device__ __forceinline__ f32x4 mfma16(s16x8 a, s16x8 b, f32x4 c) {
  return __builtin_amdgcn_mfma_f32_16x16x32_bf16(a, b, c, 0, 0, 0);
}
// async global->LDS DMA, 16 B/lane; LDS dest = wave-uniform base + lane*16
__device__ __forceinline__ void gl_lds16(const u16* g, u16* l) {
  __builtin_amdgcn_global_load_lds(
      (const __attribute__((address_space(1))) unsigned int*)g,
      (__attribute__((address_space(3))) unsigned int*)l, 16, 0, 0);
}

// -------- fp32 -> bf16 elementwise cast (float4 vectorized) -------------
__global__ __launch_bounds__(256) void k_cast(const float* __restrict__ in,
                                              u16* __restrict__ out, int n4) {
  const int i = blockIdx.x * 256 + threadIdx.x;
  if (i >= n4) return;
  const float4 v = ((const float4*)in)[i];
  ushort4 o;
  o.x = f2bf(v.x); o.y = f2bf(v.y); o.z = f2bf(v.z); o.w = f2bf(v.w);
  ((ushort4*)out)[i] = o;
}

// -------- fp32 [R][C] -> bf16 out[C][R] transpose+cast ------------------
__global__ __launch_bounds__(256) void k_transpose_cast(const float* __restrict__ in,
                                                        u16* __restrict__ out,
                                                        int R, int C) {
  __shared__ __attribute__((aligned(16))) u16 tile[32][33];
  const int c0 = blockIdx.x * 32, r0 = blockIdx.y * 32;
  const int tx = threadIdx.x, ty = threadIdx.y;
#pragma unroll
  for (int i = 0; i < 4; ++i)
    tile[ty + 8 * i][tx] = f2bf(in[(r0 + ty + 8 * i) * C + c0 + tx]);
  __syncthreads();
#pragma unroll
  for (int i = 0; i < 4; ++i)
    out[(c0 + ty + 8 * i) * R + r0 + tx] = tile[tx][ty + 8 * i];
}

// ---------------- V -> V^T per (b,h): vt[bh][d][s] = qkv_v[b,s,h,d] ------
__global__ __launch_bounds__(256) void k_vtrans(const u16* __restrict__ qkv,
                                                u16* __restrict__ vt) {
  __shared__ __attribute__((aligned(16))) u16 tile[32][33];
  const int bh = blockIdx.z, b = bh >> 4, h = bh & 15;
  const int s0 = blockIdx.x * 32, d0 = blockIdx.y * 32;
  const int tx = threadIdx.x, ty = threadIdx.y;
#pragma unroll
  for (int i = 0; i < 4; ++i) {
    const int s = s0 + ty + 8 * i;
    tile[ty + 8 * i][tx] = qkv[(b * 2048 + s) * 6144 + 4096 + h * 128 + d0 + tx];
  }
  __syncthreads();
#pragma unroll
  for (int i = 0; i < 4; ++i) {
    const int d = d0 + ty + 8 * i;
    vt[bh * 262144 + d * 2048 + s0 + tx] = tile[tx][ty + 8 * i];
  }
}

// ---------------- RoPE in-place on Q and K sections of qkv (bf16) -------
__global__ __launch_bounds__(256) void k_rope(u16* __restrict__ qkv) {
  const int id = blockIdx.x * 256 + threadIdx.x;  // 8,388,608 threads
  const int j = id & 63;
  const int h = (id >> 6) & 15;
  const int sec = (id >> 10) & 1;
  const int m = id >> 11;  // b*2048+s
  const int s = m & 2047;
  const int base = m * 6144 + sec * 2048 + h * 128 + j;
  const float q0 = bf2f(qkv[base]);
  const float q1 = bf2f(qkv[base + 64]);
  // inv_freq = 10000^(-j/64) = 2^(-j*log2(10000)/64): single v_exp_f32
  const float inv = exp2f((float)j * -0.20762050593046014f);
  const float ang = (float)s * inv;
  float c, sn;
  sincosf(ang, &sn, &c);  // sincosf(x, SIN*, COS*) — sin FIRST (r7 fix)
  qkv[base]      = f2bf(q0 * c - q1 * sn);
  qkv[base + 64] = f2bf(q1 * c + q0 * sn);
}

// ------- GEMM (m97 structure): C[M][N] = A[M][K] * BT[N][K]^T -----------
// A_F32: A is fp32, staged via VALU pack (fallback); else bf16 via
// global_load_lds. B always bf16 via global_load_lds. Unpadded pitch-32 LDS.
template <bool A_F32, typename OUT_T>
__global__ __launch_bounds__(256) void k_gemm_lds(const void* __restrict__ Ap, int lda,
                                                  const u16* __restrict__ BT,
                                                  OUT_T* __restrict__ C, int ldc,
                                                  int K) {
  __shared__ __attribute__((aligned(16))) u16 As[128 * 32];
  __shared__ __attribute__((aligned(16))) u16 Bs[128 * 32];
  const int tid = threadIdx.x;
  const int lane = tid & 63, wave = tid >> 6;
  const int lm = lane & 15, quad = lane >> 4;
  const int wm = wave >> 1, wn = wave & 1;
  const int m0 = blockIdx.y * 128, n0 = blockIdx.x * 128;
  const int srow = lane >> 2, scol = (lane & 3) * 8;  // staging map

  const f32x4 fzero = {0.f, 0.f, 0.f, 0.f};
  f32x4 acc[4][4];
#pragma unroll
  for (int i = 0; i < 4; ++i)
#pragma unroll
    for (int j = 0; j < 4; ++j) acc[i][j] = fzero;

  for (int k0 = 0; k0 < K; k0 += 32) {
    __syncthreads();
    if constexpr (A_F32) {
      const float* Af = (const float*)Ap;
#pragma unroll
      for (int i = 0; i < 2; ++i) {
        const int seg = tid + 256 * i;
        const int row = seg >> 2, c8 = (seg & 3) * 8;
        const float4 u = *(const float4*)&Af[(m0 + row) * lda + k0 + c8];
        const float4 w = *(const float4*)&Af[(m0 + row) * lda + k0 + c8 + 4];
        uint4 pk;
        pk.x = (unsigned)f2bf(u.x) | ((unsigned)f2bf(u.y) << 16);
        pk.y = (unsigned)f2bf(u.z) | ((unsigned)f2bf(u.w) << 16);
        pk.z = (unsigned)f2bf(w.x) | ((unsigned)f2bf(w.y) << 16);
        pk.w = (unsigned)f2bf(w.z) | ((unsigned)f2bf(w.w) << 16);
        *(uint4*)&As[row * 32 + c8] = pk;
      }
#pragma unroll
      for (int j = 0; j < 2; ++j) {
        const int rb = wave * 32 + j * 16;
        gl_lds16(&BT[(n0 + rb + srow) * K + k0 + scol], &Bs[rb * 32]);
      }
    } else {
      const u16* Ab = (const u16*)Ap;
#pragma unroll
      for (int j = 0; j < 2; ++j) {
        const int rb = wave * 32 + j * 16;
        gl_lds16(&Ab[(m0 + rb + srow) * lda + k0 + scol], &As[rb * 32]);
        gl_lds16(&BT[(n0 + rb + srow) * K + k0 + scol], &Bs[rb * 32]);
      }
    }
    __syncthreads();  // drains vmcnt (DMA) + lgkmcnt before reads

    s16x8 af[4], bfr[4];
#pragma unroll
    for (int t = 0; t < 4; ++t) {
      af[t]  = *(const s16x8*)&As[(wm * 64 + t * 16 + lm) * 32 + quad * 8];
      bfr[t] = *(const s16x8*)&Bs[(wn * 64 + t * 16 + lm) * 32 + quad * 8];
    }
#pragma unroll
    for (int mt = 0; mt < 4; ++mt)
#pragma unroll
      for (int nt = 0; nt < 4; ++nt)
        acc[mt][nt] = mfma16(af[mt], bfr[nt], acc[mt][nt]);
  }
  // C/D layout: row = quad*4 + r, col = lm (m89/m91)
#pragma unroll
  for (int mt = 0; mt < 4; ++mt)
#pragma unroll
    for (int nt = 0; nt < 4; ++nt)
#pragma unroll
      for (int r = 0; r < 4; ++r) {
        const float v = acc[mt][nt][r];
        const int idx = (m0 + wm * 64 + mt * 16 + quad * 4 + r) * ldc +
                        n0 + wn * 64 + nt * 16 + lm;
        if constexpr (sizeof(OUT_T) == 2) C[idx] = f2bf(v);
        else                              C[idx] = v;
      }
}

// ---------------- causal flash attention (bf16 in/out) ------------------
// (unchanged from round 7 — verified correct)
__global__ __launch_bounds__(256) void k_attn(u16* __restrict__ qkv,
                                              const u16* __restrict__ vt) {
  __shared__ __attribute__((aligned(16))) u16 Ks[32 * 136];     // [32 keys][128 d]
  __shared__ __attribute__((aligned(16))) u16 Vs[128 * 40];     // [128 d][32 keys]
  __shared__ __attribute__((aligned(16))) u16 Ps[4 * 16 * 40];  // per-wave P[q][key]
  const int qtile = blockIdx.x, bh = blockIdx.y;
  const int b = bh >> 4, h = bh & 15;
  const int tid = threadIdx.x;
  const int lane = tid & 63, wave = tid >> 6;
  const int lm = lane & 15, quad = lane >> 4;
  const int qb = qtile * 64;
  const int qrow = qb + wave * 16 + lm;
  const int pbase = wave * 640;

  s16x8 qfrag[4];
  const int qoff = (b * 2048 + qrow) * 6144 + h * 128;
#pragma unroll
  for (int c = 0; c < 4; ++c)
    qfrag[c] = *(const s16x8*)&qkv[qoff + c * 32 + quad * 8];

  const f32x4 fzero = {0.f, 0.f, 0.f, 0.f};
  f32x4 o[8];
#pragma unroll
  for (int dt = 0; dt < 8; ++dt) o[dt] = fzero;
  float m_run = NEG_BIG, l_run = 0.f;

  const int nkt = (qb >> 5) + 2;  // key tiles covering 0 .. qb+63
  for (int kt = 0; kt < nkt; ++kt) {
    const int kt0 = kt * 32;
    __syncthreads();
#pragma unroll
    for (int i = 0; i < 2; ++i) {
      const int seg = tid + 256 * i;
      {  // K tile
        const int row = seg >> 4, c8 = (seg & 15) * 8;
        *(uint4*)&Ks[row * 136 + c8] =
            *(const uint4*)&qkv[(b * 2048 + kt0 + row) * 6144 + 2048 + h * 128 + c8];
      }
      {  // V^T tile
        const int row = seg >> 2, c8 = (seg & 3) * 8;
        *(uint4*)&Vs[row * 40 + c8] =
            *(const uint4*)&vt[bh * 262144 + row * 2048 + kt0 + c8];
      }
    }
    __syncthreads();

    f32x4 sa[2];
    sa[0] = fzero; sa[1] = fzero;
#pragma unroll
    for (int ss = 0; ss < 2; ++ss)
#pragma unroll
      for (int c = 0; c < 4; ++c) {
        s16x8 a = *(const s16x8*)&Ks[(ss * 16 + lm) * 136 + c * 32 + quad * 8];
        sa[ss] = mfma16(a, qfrag[c], sa[ss]);
      }

    float p[2][4];
    float vmax = NEG_BIG;
#pragma unroll
    for (int ss = 0; ss < 2; ++ss)
#pragma unroll
      for (int r = 0; r < 4; ++r) {
        const int kg = kt0 + ss * 16 + quad * 4 + r;
        float v = sa[ss][r] * ATTN_SCALE;
        if (kg > qrow) v = NEG_BIG;
        p[ss][r] = v;
        vmax = fmaxf(vmax, v);
      }
    vmax = fmaxf(vmax, __shfl_xor(vmax, 16, 64));
    vmax = fmaxf(vmax, __shfl_xor(vmax, 32, 64));
    const float m_new = fmaxf(m_run, vmax);
    const float alpha = __expf(m_run - m_new);
    float rsum = 0.f;
#pragma unroll
    for (int ss = 0; ss < 2; ++ss)
#pragma unroll
      for (int r = 0; r < 4; ++r) {
        p[ss][r] = __expf(p[ss][r] - m_new);  // masked: exp(-huge) = 0
        rsum += p[ss][r];
      }
    rsum += __shfl_xor(rsum, 16, 64);
    rsum += __shfl_xor(rsum, 32, 64);
    l_run = l_run * alpha + rsum;
    m_run = m_new;
#pragma unroll
    for (int dt = 0; dt < 8; ++dt) o[dt] *= alpha;

    // P -> LDS: Ps[q=lm][key = ss*16 + quad*4 + r]
#pragma unroll
    for (int ss = 0; ss < 2; ++ss)
#pragma unroll
      for (int r = 0; r < 4; ++r)
        Ps[pbase + lm * 40 + ss * 16 + quad * 4 + r] = f2bf(p[ss][r]);

    __syncthreads();  // cross-lane LDS RAW guard

    const s16x8 pv = *(const s16x8*)&Ps[pbase + lm * 40 + quad * 8];

#pragma unroll
    for (int dt = 0; dt < 8; ++dt) {
      s16x8 a = *(const s16x8*)&Vs[(dt * 16 + lm) * 40 + quad * 8];
      o[dt] = mfma16(a, pv, o[dt]);
    }
  }

  const float inv_l = 1.0f / l_run;
#pragma unroll
  for (int dt = 0; dt < 8; ++dt)
#pragma unroll
    for (int r = 0; r < 4; ++r)
      qkv[qoff + dt * 16 + quad * 4 + r] = f2bf(o[dt][r] * inv_l);
}

// ---------------- host launcher ----------------------------------------
extern "C" void kernel_launch(void* const* d_in, const int* in_sizes, int n_in,
                              void* d_out, int out_size, void* d_ws, size_t ws_size,
                              hipStream_t stream) {
  const float* hidden = (const float*)d_in[0];  // [4096][2048] fp32
  const float* w_qkv  = (const float*)d_in[1];  // [2048][6144] fp32
  const float* w_o    = (const float*)d_in[2];  // [2048][2048] fp32
  float* out = (float*)d_out;                   // [4096][2048] fp32
  u16* ws = (u16*)d_ws;

  // Base overlay (72 MB):
  //   qkv   : [0, 25165824)          whole session
  //   wqkvT : [25165824, 37748736)   GEMM1 only
  //   vt    : [25165824, 33554432)   after GEMM1 (overlays wqkvT head)
  //   woT   : [33554432, 37748736)   after GEMM1 (overlays wqkvT tail)
  // Fast path adds hb (bf16 hidden): [37748736, 46137344) -> peak 92.3 MB
  u16* qkv   = ws;
  u16* wqkvT = ws + 25165824;
  u16* vt    = ws + 25165824;
  u16* woT   = ws + 33554432;
  u16* hb    = ws + 37748736;
  const bool fast = ws_size >= (size_t)46137344 * 2;

  dim3 tb(32, 8);
  k_transpose_cast<<<dim3(192, 64), tb, 0, stream>>>(w_qkv, wqkvT, 2048, 6144);
  if (fast) {
    k_cast<<<8192, 256, 0, stream>>>(hidden, hb, 2097152);
    k_gemm_lds<false, u16><<<dim3(48, 32), 256, 0, stream>>>(hb, 2048, wqkvT,
                                                             qkv, 6144, 2048);
  } else {
    k_gemm_lds<true, u16><<<dim3(48, 32), 256, 0, stream>>>(hidden, 2048, wqkvT,
                                                            qkv, 6144, 2048);
  }
  k_rope<<<32768, 256, 0, stream>>>(qkv);
  k_vtrans<<<dim3(64, 4, 32), tb, 0, stream>>>(qkv, vt);
  k_transpose_cast<<<dim3(64, 64), tb, 0, stream>>>(w_o, woT, 2048, 2048);
  k_attn<<<dim3(32, 32), 256, 0, stream>>>(qkv, vt);
  k_gemm_lds<false, float><<<dim3(16, 32), 256, 0, stream>>>(qkv, 6144, woT,
                                                             out, 2048, 2048);
}

// Round 9
// 487.726 us; speedup vs baseline: 1.1151x; 1.0186x over previous
//
#include <hip/hip_runtime.h>
#include <math.h>

typedef unsigned short u16;
typedef short s16x8 __attribute__((ext_vector_type(8)));  // 8 bf16 lanes (4 VGPRs)
typedef float f32x4 __attribute__((ext_vector_type(4)));

// B=2, S=2048, D=2048, H=16, HD=128; qkv row width = 6144
#define ATTN_SCALE 0.08838834764831845f
#define NEG_BIG -1.0e30f

__device__ __forceinline__ u16 f2bf(float f) {
  union { float f; unsigned u; } c; c.f = f;
  return (u16)((c.u + 0x7fffu + ((c.u >> 16) & 1u)) >> 16);  // RNE
}
__device__ __forceinline__ float bf2f(u16 v) {
  union { unsigned u; float f; } c; c.u = ((unsigned)v) << 16;
  return c.f;
}
__device__ __forceinline__ f32x4 mfma16(s16x8 a, s16x8 b, f32x4 c) {
  return __builtin_amdgcn_mfma_f32_16x16x32_bf16(a, b, c, 0, 0, 0);
}
// async global->LDS DMA, 16 B/lane; LDS dest = wave-uniform base + lane*16
__device__ __forceinline__ void gl_lds16(const u16* g, u16* l) {
  __builtin_amdgcn_global_load_lds(
      (const __attribute__((address_space(1))) unsigned int*)g,
      (__attribute__((address_space(3))) unsigned int*)l, 16, 0, 0);
}

// -------- fp32 -> bf16 elementwise cast (float4 vectorized) -------------
__global__ __launch_bounds__(256) void k_cast(const float* __restrict__ in,
                                              u16* __restrict__ out, int n4) {
  const int i = blockIdx.x * 256 + threadIdx.x;
  if (i >= n4) return;
  const float4 v = ((const float4*)in)[i];
  ushort4 o;
  o.x = f2bf(v.x); o.y = f2bf(v.y); o.z = f2bf(v.z); o.w = f2bf(v.w);
  ((ushort4*)out)[i] = o;
}

// -------- fp32 [R][C] -> bf16 out[C][R] transpose+cast ------------------
__global__ __launch_bounds__(256) void k_transpose_cast(const float* __restrict__ in,
                                                        u16* __restrict__ out,
                                                        int R, int C) {
  __shared__ __attribute__((aligned(16))) u16 tile[32][33];
  const int c0 = blockIdx.x * 32, r0 = blockIdx.y * 32;
  const int tx = threadIdx.x, ty = threadIdx.y;
#pragma unroll
  for (int i = 0; i < 4; ++i)
    tile[ty + 8 * i][tx] = f2bf(in[(r0 + ty + 8 * i) * C + c0 + tx]);
  __syncthreads();
#pragma unroll
  for (int i = 0; i < 4; ++i)
    out[(c0 + ty + 8 * i) * R + r0 + tx] = tile[tx][ty + 8 * i];
}

// ---------------- V -> V^T per (b,h): vt[bh][d][s] = qkv_v[b,s,h,d] ------
__global__ __launch_bounds__(256) void k_vtrans(const u16* __restrict__ qkv,
                                                u16* __restrict__ vt) {
  __shared__ __attribute__((aligned(16))) u16 tile[32][33];
  const int bh = blockIdx.z, b = bh >> 4, h = bh & 15;
  const int s0 = blockIdx.x * 32, d0 = blockIdx.y * 32;
  const int tx = threadIdx.x, ty = threadIdx.y;
#pragma unroll
  for (int i = 0; i < 4; ++i) {
    const int s = s0 + ty + 8 * i;
    tile[ty + 8 * i][tx] = qkv[(b * 2048 + s) * 6144 + 4096 + h * 128 + d0 + tx];
  }
  __syncthreads();
#pragma unroll
  for (int i = 0; i < 4; ++i) {
    const int d = d0 + ty + 8 * i;
    vt[bh * 262144 + d * 2048 + s0 + tx] = tile[tx][ty + 8 * i];
  }
}

// ---------------- RoPE in-place on Q and K sections of qkv (bf16) -------
__global__ __launch_bounds__(256) void k_rope(u16* __restrict__ qkv) {
  const int id = blockIdx.x * 256 + threadIdx.x;  // 8,388,608 threads
  const int j = id & 63;
  const int h = (id >> 6) & 15;
  const int sec = (id >> 10) & 1;
  const int m = id >> 11;  // b*2048+s
  const int s = m & 2047;
  const int base = m * 6144 + sec * 2048 + h * 128 + j;
  const float q0 = bf2f(qkv[base]);
  const float q1 = bf2f(qkv[base + 64]);
  const float inv = exp2f((float)j * -0.20762050593046014f);  // 10000^(-j/64)
  const float ang = (float)s * inv;
  float c, sn;
  sincosf(ang, &sn, &c);  // sincosf(x, SIN*, COS*) — sin FIRST
  qkv[base]      = f2bf(q0 * c - q1 * sn);
  qkv[base + 64] = f2bf(q1 * c + q0 * sn);
}

// ------- GEMM (m97 structure): C[M][N] = A[M][K] * BT[N][K]^T -----------
template <bool A_F32, typename OUT_T>
__global__ __launch_bounds__(256) void k_gemm_lds(const void* __restrict__ Ap, int lda,
                                                  const u16* __restrict__ BT,
                                                  OUT_T* __restrict__ C, int ldc,
                                                  int K) {
  __shared__ __attribute__((aligned(16))) u16 As[128 * 32];
  __shared__ __attribute__((aligned(16))) u16 Bs[128 * 32];
  const int tid = threadIdx.x;
  const int lane = tid & 63, wave = tid >> 6;
  const int lm = lane & 15, quad = lane >> 4;
  const int wm = wave >> 1, wn = wave & 1;
  const int m0 = blockIdx.y * 128, n0 = blockIdx.x * 128;
  const int srow = lane >> 2, scol = (lane & 3) * 8;  // staging map

  const f32x4 fzero = {0.f, 0.f, 0.f, 0.f};
  f32x4 acc[4][4];
#pragma unroll
  for (int i = 0; i < 4; ++i)
#pragma unroll
    for (int j = 0; j < 4; ++j) acc[i][j] = fzero;

  for (int k0 = 0; k0 < K; k0 += 32) {
    __syncthreads();
    if constexpr (A_F32) {
      const float* Af = (const float*)Ap;
#pragma unroll
      for (int i = 0; i < 2; ++i) {
        const int seg = tid + 256 * i;
        const int row = seg >> 2, c8 = (seg & 3) * 8;
        const float4 u = *(const float4*)&Af[(m0 + row) * lda + k0 + c8];
        const float4 w = *(const float4*)&Af[(m0 + row) * lda + k0 + c8 + 4];
        uint4 pk;
        pk.x = (unsigned)f2bf(u.x) | ((unsigned)f2bf(u.y) << 16);
        pk.y = (unsigned)f2bf(u.z) | ((unsigned)f2bf(u.w) << 16);
        pk.z = (unsigned)f2bf(w.x) | ((unsigned)f2bf(w.y) << 16);
        pk.w = (unsigned)f2bf(w.z) | ((unsigned)f2bf(w.w) << 16);
        *(uint4*)&As[row * 32 + c8] = pk;
      }
#pragma unroll
      for (int j = 0; j < 2; ++j) {
        const int rb = wave * 32 + j * 16;
        gl_lds16(&BT[(n0 + rb + srow) * K + k0 + scol], &Bs[rb * 32]);
      }
    } else {
      const u16* Ab = (const u16*)Ap;
#pragma unroll
      for (int j = 0; j < 2; ++j) {
        const int rb = wave * 32 + j * 16;
        gl_lds16(&Ab[(m0 + rb + srow) * lda + k0 + scol], &As[rb * 32]);
        gl_lds16(&BT[(n0 + rb + srow) * K + k0 + scol], &Bs[rb * 32]);
      }
    }
    __syncthreads();  // drains vmcnt (DMA) + lgkmcnt before reads

    s16x8 af[4], bfr[4];
#pragma unroll
    for (int t = 0; t < 4; ++t) {
      af[t]  = *(const s16x8*)&As[(wm * 64 + t * 16 + lm) * 32 + quad * 8];
      bfr[t] = *(const s16x8*)&Bs[(wn * 64 + t * 16 + lm) * 32 + quad * 8];
    }
#pragma unroll
    for (int mt = 0; mt < 4; ++mt)
#pragma unroll
      for (int nt = 0; nt < 4; ++nt)
        acc[mt][nt] = mfma16(af[mt], bfr[nt], acc[mt][nt]);
  }
#pragma unroll
  for (int mt = 0; mt < 4; ++mt)
#pragma unroll
    for (int nt = 0; nt < 4; ++nt)
#pragma unroll
      for (int r = 0; r < 4; ++r) {
        const float v = acc[mt][nt][r];
        const int idx = (m0 + wm * 64 + mt * 16 + quad * 4 + r) * ldc +
                        n0 + wn * 64 + nt * 16 + lm;
        if constexpr (sizeof(OUT_T) == 2) C[idx] = f2bf(v);
        else                              C[idx] = v;
      }
}

// ---------------- causal flash attention, v2 ----------------------------
// 64-key tiles (half the iterations), causal PAIRING: block handles
// qtiles {pair, 31-pair} -> exactly 33 key-tile iterations per block,
// perfectly uniform. P-bounce is wave-private (no barrier needed).
__global__ __launch_bounds__(256) void k_attn(u16* __restrict__ qkv,
                                              const u16* __restrict__ vt) {
  __shared__ __attribute__((aligned(16))) u16 Ks[64 * 136];      // [64 keys][128 d]
  __shared__ __attribute__((aligned(16))) u16 Vs[128 * 72];      // [128 d][64 keys]
  __shared__ __attribute__((aligned(16))) u16 Ps[4 * 16 * 72];   // per-wave P[q][key]
  const int pair = blockIdx.x, bh = blockIdx.y;
  const int b = bh >> 4, h = bh & 15;
  const int tid = threadIdx.x;
  const int lane = tid & 63, wave = tid >> 6;
  const int lm = lane & 15, quad = lane >> 4;
  const int pbase = wave * 1152;  // wave-private P region (u16 units)
  const f32x4 fzero = {0.f, 0.f, 0.f, 0.f};

  for (int phase = 0; phase < 2; ++phase) {
    const int qtile = phase ? (31 - pair) : pair;
    const int qb = qtile * 64;
    const int qrow = qb + wave * 16 + lm;
    const int qoff = (b * 2048 + qrow) * 6144 + h * 128;

    s16x8 qfrag[4];
#pragma unroll
    for (int c = 0; c < 4; ++c)
      qfrag[c] = *(const s16x8*)&qkv[qoff + c * 32 + quad * 8];

    f32x4 o[8];
#pragma unroll
    for (int dt = 0; dt < 8; ++dt) o[dt] = fzero;
    float m_run = NEG_BIG, l_run = 0.f;

    for (int kt = 0; kt <= qtile; ++kt) {  // 64-key tiles covering 0..qb+63
      const int kt0 = kt * 64;
      __syncthreads();  // prior iteration's reads done before restage
#pragma unroll
      for (int i = 0; i < 4; ++i) {
        const int seg = tid + 256 * i;
        {  // K tile: [64 keys][128 d]
          const int row = seg >> 4, c8 = (seg & 15) * 8;
          *(uint4*)&Ks[row * 136 + c8] =
              *(const uint4*)&qkv[(b * 2048 + kt0 + row) * 6144 + 2048 + h * 128 + c8];
        }
        {  // V^T tile: [128 d][64 keys]
          const int row = seg >> 3, c8 = (seg & 7) * 8;
          *(uint4*)&Vs[row * 72 + c8] =
              *(const uint4*)&vt[bh * 262144 + row * 2048 + kt0 + c8];
        }
      }
      __syncthreads();

      // S^T[key][q]: 4 sub-tiles of 16 keys
      f32x4 sa[4];
#pragma unroll
      for (int ss = 0; ss < 4; ++ss) sa[ss] = fzero;
#pragma unroll
      for (int ss = 0; ss < 4; ++ss)
#pragma unroll
        for (int c = 0; c < 4; ++c) {
          s16x8 a = *(const s16x8*)&Ks[(ss * 16 + lm) * 136 + c * 32 + quad * 8];
          sa[ss] = mfma16(a, qfrag[c], sa[ss]);
        }

      // scale + causal mask + online softmax (per column q = lm)
      float p[4][4];
      float vmax = NEG_BIG;
#pragma unroll
      for (int ss = 0; ss < 4; ++ss)
#pragma unroll
        for (int r = 0; r < 4; ++r) {
          const int kg = kt0 + ss * 16 + quad * 4 + r;
          float v = sa[ss][r] * ATTN_SCALE;
          if (kg > qrow) v = NEG_BIG;
          p[ss][r] = v;
          vmax = fmaxf(vmax, v);
        }
      vmax = fmaxf(vmax, __shfl_xor(vmax, 16, 64));
      vmax = fmaxf(vmax, __shfl_xor(vmax, 32, 64));
      const float m_new = fmaxf(m_run, vmax);
      const float alpha = __expf(m_run - m_new);
      float rsum = 0.f;
#pragma unroll
      for (int ss = 0; ss < 4; ++ss)
#pragma unroll
        for (int r = 0; r < 4; ++r) {
          p[ss][r] = __expf(p[ss][r] - m_new);  // masked: exp(-huge) = 0
          rsum += p[ss][r];
        }
      rsum += __shfl_xor(rsum, 16, 64);
      rsum += __shfl_xor(rsum, 32, 64);
      l_run = l_run * alpha + rsum;
      m_run = m_new;
#pragma unroll
      for (int dt = 0; dt < 8; ++dt) o[dt] *= alpha;

      // P -> wave-private LDS: Ps[q=lm][key = ss*16 + quad*4 + r]
      // (intra-wave DS ordering: no barrier needed)
#pragma unroll
      for (int ss = 0; ss < 4; ++ss)
#pragma unroll
        for (int r = 0; r < 4; ++r)
          Ps[pbase + lm * 72 + ss * 16 + quad * 4 + r] = f2bf(p[ss][r]);

      const s16x8 pv0 = *(const s16x8*)&Ps[pbase + lm * 72 + quad * 8];
      const s16x8 pv1 = *(const s16x8*)&Ps[pbase + lm * 72 + 32 + quad * 8];

      // O^T += V^T * P^T over the two 32-key halves
#pragma unroll
      for (int dt = 0; dt < 8; ++dt) {
        s16x8 a0 = *(const s16x8*)&Vs[(dt * 16 + lm) * 72 + quad * 8];
        s16x8 a1 = *(const s16x8*)&Vs[(dt * 16 + lm) * 72 + 32 + quad * 8];
        o[dt] = mfma16(a1, pv1, mfma16(a0, pv0, o[dt]));
      }
    }

    const float inv_l = 1.0f / l_run;
#pragma unroll
    for (int dt = 0; dt < 8; ++dt)
#pragma unroll
      for (int r = 0; r < 4; ++r)
        qkv[qoff + dt * 16 + quad * 4 + r] = f2bf(o[dt][r] * inv_l);
  }
}

// ---------------- host launcher ----------------------------------------
extern "C" void kernel_launch(void* const* d_in, const int* in_sizes, int n_in,
                              void* d_out, int out_size, void* d_ws, size_t ws_size,
                              hipStream_t stream) {
  const float* hidden = (const float*)d_in[0];  // [4096][2048] fp32
  const float* w_qkv  = (const float*)d_in[1];  // [2048][6144] fp32
  const float* w_o    = (const float*)d_in[2];  // [2048][2048] fp32
  float* out = (float*)d_out;                   // [4096][2048] fp32
  u16* ws = (u16*)d_ws;

  u16* qkv   = ws;
  u16* wqkvT = ws + 25165824;
  u16* vt    = ws + 25165824;
  u16* woT   = ws + 33554432;
  u16* hb    = ws + 37748736;
  const bool fast = ws_size >= (size_t)46137344 * 2;

  dim3 tb(32, 8);
  k_transpose_cast<<<dim3(192, 64), tb, 0, stream>>>(w_qkv, wqkvT, 2048, 6144);
  if (fast) {
    k_cast<<<8192, 256, 0, stream>>>(hidden, hb, 2097152);
    k_gemm_lds<false, u16><<<dim3(48, 32), 256, 0, stream>>>(hb, 2048, wqkvT,
                                                             qkv, 6144, 2048);
  } else {
    k_gemm_lds<true, u16><<<dim3(48, 32), 256, 0, stream>>>(hidden, 2048, wqkvT,
                                                            qkv, 6144, 2048);
  }
  k_rope<<<32768, 256, 0, stream>>>(qkv);
  k_vtrans<<<dim3(64, 4, 32), tb, 0, stream>>>(qkv, vt);
  k_transpose_cast<<<dim3(64, 64), tb, 0, stream>>>(w_o, woT, 2048, 2048);
  k_attn<<<dim3(16, 32), 256, 0, stream>>>(qkv, vt);
  k_gemm_lds<false, float><<<dim3(16, 32), 256, 0, stream>>>(qkv, 6144, woT,
                                                             out, 2048, 2048);
}